// Round 18
// baseline (150.722 us; speedup 1.0000x reference)
//
#include <hip/hip_runtime.h>
#include <math.h>

#define N_NODES 80000
#define N_EDGES 1280000
#define D_NODE  128
#define D_EDGE  32
#define D_HID   64
#define NEG_SLOPE 0.2f
#define NB 313              // buckets of 256 target nodes
#define CAP 4608            // slab capacity per bucket (mean 4096 + 8 sigma)
#define BCNT_STRIDE 16      // one counter per 64B line
#define EB_BLK 512
#define EB_CHUNK 2048
#define EB_NCHUNK (N_EDGES / EB_CHUNK)   // 625, exact

__device__ inline float waveReduceSum(float v) {
    #pragma unroll
    for (int o = 32; o > 0; o >>= 1) v += __shfl_xor(v, o);
    return v;
}
__device__ inline unsigned short f2bf(float f) {   // round-to-nearest-even bf16
    unsigned u = __float_as_uint(f);
    return (unsigned short)((u + 0x7FFF + ((u >> 16) & 1)) >> 16);
}
__device__ inline float bf2f(unsigned short v) {
    return __uint_as_float(((unsigned)v) << 16);
}

// h(bf16) = nf @ W + b; s1 = h . a1; s2 = h . a2 (f32, pre-rounding)
__global__ __launch_bounds__(256) void node_kernel(
        const float* __restrict__ nf, const float* __restrict__ w_w,
        const float* __restrict__ w_b, const float* __restrict__ a_w,
        unsigned short* __restrict__ hb, float* __restrict__ s1, float* __restrict__ s2) {
    __shared__ float Ws[D_HID * D_NODE];   // 32 KB, XOR-swizzled W^T
    __shared__ float Xs[32][D_NODE];       // 16 KB
    for (int i = threadIdx.x; i < D_NODE * D_HID; i += 256) {
        int k = i >> 6, d = i & 63;        // w_w[k][d], row-major [128][64]
        Ws[d * D_NODE + (((k >> 2) ^ (d & 7)) << 2) + (k & 3)] = w_w[i];
    }
    int lane = threadIdx.x & 63;
    int wv   = threadIdx.x >> 6;
    float wb = w_b[lane];
    float a1 = a_w[lane];
    float a2 = a_w[D_HID + lane];
    const float* wrow = &Ws[lane * D_NODE];
    const int nTiles = N_NODES / 32;       // 2500, exact
    for (int tile = blockIdx.x; tile < nTiles; tile += gridDim.x) {
        int n0 = tile * 32;
        __syncthreads();
        {
            const float4* src = (const float4*)(nf + (size_t)n0 * D_NODE);
            float4* dst = (float4*)&Xs[0][0];
            #pragma unroll
            for (int j = 0; j < 4; ++j)
                dst[threadIdx.x + 256 * j] = src[threadIdx.x + 256 * j];
        }
        __syncthreads();
        float acc[8] = {0.f, 0.f, 0.f, 0.f, 0.f, 0.f, 0.f, 0.f};
        const float* xs = &Xs[wv * 8][0];
        #pragma unroll 4
        for (int k4 = 0; k4 < 32; ++k4) {
            float4 w = *(const float4*)&wrow[(k4 ^ (lane & 7)) << 2];
            #pragma unroll
            for (int n = 0; n < 8; ++n) {
                float4 x = *(const float4*)&xs[n * D_NODE + (k4 << 2)];
                acc[n] += w.x * x.x + w.y * x.y + w.z * x.z + w.w * x.w;
            }
        }
        #pragma unroll
        for (int n = 0; n < 8; ++n) {
            int node = n0 + wv * 8 + n;
            float hv = acc[n] + wb;
            hb[(size_t)node * D_HID + lane] = f2bf(hv);
            float r1 = waveReduceSum(hv * a1);
            float r2 = waveReduceSum(hv * a2);
            if (lane == 0) { s1[node] = r1; s2[node] = r2; }
        }
    }
}

// Edge score + bin, latency-optimized:
//  - s2[nbr] deferred to accum -> Phase A (eidx+hist) and Phase B (ef dot)
//    share one barrier-free region (A never touches sq).
//  - Phase B: two half-passes of 8 FULLY-UNROLLED rounds; 16 float4 loads
//    issued back-to-back into registers before any compute -> 4x deeper MLP
//    than the previous #pragma unroll 2.
//  - Phase C/D: reserve + LDS-permute + linear coalesced store (R16).
__global__ __launch_bounds__(EB_BLK) void edge_bin_kernel(
        const float* __restrict__ ef, const int* __restrict__ eidx,
        const float* __restrict__ ew_w, const float* __restrict__ ew_b,
        const float* __restrict__ a_w, const float* __restrict__ a_b,
        int* __restrict__ bcnt, int2* __restrict__ binned) {
    __shared__ float cs[D_EDGE];
    __shared__ float besp;
    __shared__ int hist[NB], gbase[NB], rank[NB];
    __shared__ int scanbuf[512];
    __shared__ float sq [EB_CHUNK];   // 8 KB: q = ef.c + bes
    __shared__ int2  sval[EB_CHUNK];  // 16 KB
    __shared__ int   sdst[EB_CHUNK];  // 8 KB
    int tid = threadIdx.x;
    if (tid < D_EDGE) {
        float s = 0.f;
        #pragma unroll
        for (int d = 0; d < D_HID; ++d) s += ew_w[tid * D_HID + d] * a_w[2 * D_HID + d];
        cs[tid] = s;
    } else if (tid == D_EDGE) {
        float s = 0.f;
        #pragma unroll
        for (int d = 0; d < D_HID; ++d) s += ew_b[d] * a_w[2 * D_HID + d];
        besp = s + a_b[0];
    }
    for (int i = tid; i < NB; i += EB_BLK) { hist[i] = 0; rank[i] = 0; }
    __syncthreads();
    float bes = besp;
    int e0 = blockIdx.x * EB_CHUNK;        // one chunk per block, grid = 625
    // ---- Phase A (no barrier after): coalesced eidx loads -> regs + hist ----
    int RT[4], RN[4];
    #pragma unroll
    for (int k = 0; k < 4; ++k) {
        int idx = k * EB_BLK + tid;
        int e = e0 + idx;
        RT[k] = eidx[e];
        RN[k] = eidx[N_EDGES + e];
        atomicAdd(&hist[RT[k] >> 8], 1);
    }
    // ---- Phase B (same region): ef dot, 2 half-passes x 8 unrolled rounds ----
    {
        int qd = tid >> 2, j = tid & 3;
        const float4 c1 = *(const float4*)&cs[j * 4];
        const float4 c2 = *(const float4*)&cs[16 + j * 4];
        const float4* f4 = (const float4*)ef;
        #pragma unroll
        for (int half = 0; half < 2; ++half) {
            float4 FA[8], FB[8];
            #pragma unroll
            for (int rr = 0; rr < 8; ++rr) {           // 16 loads issued back-to-back
                int idx = (half * 8 + rr) * 128 + qd;
                size_t e = (size_t)(e0 + idx);
                FA[rr] = f4[e * 8 + j];
                FB[rr] = f4[e * 8 + 4 + j];
            }
            #pragma unroll
            for (int rr = 0; rr < 8; ++rr) {
                int idx = (half * 8 + rr) * 128 + qd;
                float p = FA[rr].x * c1.x + FA[rr].y * c1.y + FA[rr].z * c1.z + FA[rr].w * c1.w
                        + FB[rr].x * c2.x + FB[rr].y * c2.y + FB[rr].z * c2.z + FB[rr].w * c2.w;
                p += __shfl_xor(p, 1);
                p += __shfl_xor(p, 2);
                if (j == 0) sq[idx] = p + bes;
            }
        }
    }
    __syncthreads();
    // ---- Phase C: reserve global ranges + local scan of hist ----
    for (int i = tid; i < NB; i += EB_BLK) {
        int cc = hist[i];
        if (cc) gbase[i] = i * CAP + atomicAdd(&bcnt[i * BCNT_STRIDE], cc);
    }
    scanbuf[tid] = (tid < NB) ? hist[tid] : 0;
    __syncthreads();
    for (int ofs = 1; ofs < 512; ofs <<= 1) {
        int t = (tid >= (unsigned)ofs) ? scanbuf[tid - ofs] : 0;
        __syncthreads();
        scanbuf[tid] += t;
        __syncthreads();
    }
    // ---- Phase D1: scatter {meta,q}+dest into LDS slab (slab order) ----
    #pragma unroll
    for (int k = 0; k < 4; ++k) {
        int idx = k * EB_BLK + tid;
        int tg = RT[k];
        int b  = tg >> 8;
        int r  = atomicAdd(&rank[b], 1);
        int slot = scanbuf[b] - hist[b] + r;
        sval[slot] = make_int2(((tg & 255) << 17) | RN[k],
                               __float_as_int(sq[idx]));
        sdst[slot] = gbase[b] + r;
    }
    __syncthreads();
    // ---- Phase D2: linear sweep -> ascending-address coalesced stores ----
    #pragma unroll
    for (int k = 0; k < 4; ++k) {
        int i = k * EB_BLK + tid;
        binned[sdst[i]] = sval[i];
    }
}

// Merged CSR + accum with deferred s2 (R17, measured ~15 us):
// s = s1[node] + q + s2[nbr]; leaky; exp; weighted bf16 h-row gather; elu.
__global__ __launch_bounds__(1024) void bucket_accum_kernel(
        const int* __restrict__ bcnt, const int2* __restrict__ binned,
        const float* __restrict__ s1, const float* __restrict__ s2v,
        const unsigned short* __restrict__ hb, float* __restrict__ out) {
    __shared__ int nhist[256], buf[256], sbase[256], ncur[256];
    __shared__ int2 slab[CAP];        // 36 KB
    int tid = threadIdx.x;
    int b = blockIdx.x;
    int in0 = b * CAP;
    int cnt = bcnt[b * BCNT_STRIDE];
    if (tid < 256) nhist[tid] = 0;
    __syncthreads();
    for (int i = tid; i < cnt; i += 1024)
        atomicAdd(&nhist[binned[in0 + i].x >> 17], 1);
    __syncthreads();
    if (tid < 256) buf[tid] = nhist[tid];
    __syncthreads();
    for (int ofs = 1; ofs < 256; ofs <<= 1) {
        int t = 0;
        if (tid < 256 && tid >= ofs) t = buf[tid - ofs];
        __syncthreads();
        if (tid < 256) buf[tid] += t;
        __syncthreads();
    }
    if (tid < 256) {
        int excl = buf[tid] - nhist[tid];
        sbase[tid] = excl;
        ncur[tid]  = excl;
    }
    __syncthreads();
    for (int i = tid; i < cnt; i += 1024) {
        int2 p = binned[in0 + i];
        int r = atomicAdd(&ncur[p.x >> 17], 1);
        slab[r] = make_int2(p.x & 0x1FFFF, p.y);   // {nbr, q bits}
    }
    __syncthreads();
    int grp = tid >> 4;               // 0..63
    int li  = tid & 15;
    int wl  = ((tid & 63) >> 4) << 4; // group base lane within wave
    for (int nl = grp; nl < 256; nl += 64) {
        int node = b * 256 + nl;
        if (node >= N_NODES) break;
        int base = sbase[nl];
        int cn   = nhist[nl];
        float s1i = s1[node];
        float ax = 0.f, ay = 0.f, az = 0.f, aw = 0.f, sumex = 0.f;
        for (int c0 = 0; c0 < cn; c0 += 16) {
            int i = c0 + li;
            int nc = min(16, cn - c0);
            float exv = 0.f; int nbv = 0;
            if (i < cn) {
                int2 p = slab[base + i];
                nbv = p.x;
                float s = s1i + __int_as_float(p.y) + s2v[nbv];  // deferred s2
                s = (s > 0.f) ? s : NEG_SLOPE * s;
                exv = __expf(s);      // un-normalized (exp safe in f32)
            }
            sumex += exv;
            for (int jj = 0; jj < nc; ++jj) {
                float w  = __shfl(exv, wl + jj);
                int   nb = __shfl(nbv, wl + jj);
                uint2 v = *(const uint2*)&hb[(size_t)nb * D_HID + li * 4];
                ax += w * bf2f((unsigned short)(v.x & 0xFFFF));
                ay += w * bf2f((unsigned short)(v.x >> 16));
                az += w * bf2f((unsigned short)(v.y & 0xFFFF));
                aw += w * bf2f((unsigned short)(v.y >> 16));
            }
        }
        #pragma unroll
        for (int o = 8; o > 0; o >>= 1) sumex += __shfl_xor(sumex, o);
        float4 o4;
        if (cn == 0) {
            o4 = make_float4(0.f, 0.f, 0.f, 0.f);
        } else {
            o4.x = ax / sumex; o4.y = ay / sumex; o4.z = az / sumex; o4.w = aw / sumex;
            o4.x = (o4.x > 0.f) ? o4.x : (__expf(o4.x) - 1.f);
            o4.y = (o4.y > 0.f) ? o4.y : (__expf(o4.y) - 1.f);
            o4.z = (o4.z > 0.f) ? o4.z : (__expf(o4.z) - 1.f);
            o4.w = (o4.w > 0.f) ? o4.w : (__expf(o4.w) - 1.f);
        }
        ((float4*)out)[(size_t)node * 16 + li] = o4;
    }
}

extern "C" void kernel_launch(void* const* d_in, const int* in_sizes, int n_in,
                              void* d_out, int out_size, void* d_ws, size_t ws_size,
                              hipStream_t stream) {
    const float* nf   = (const float*)d_in[0];
    const float* ef   = (const float*)d_in[1];
    const int*   eidx = (const int*)d_in[2];
    const float* w_w  = (const float*)d_in[3];
    const float* w_b  = (const float*)d_in[4];
    const float* ew_w = (const float*)d_in[5];
    const float* ew_b = (const float*)d_in[6];
    const float* a_w  = (const float*)d_in[7];
    const float* a_b  = (const float*)d_in[8];
    float* out = (float*)d_out;

    char* ws = (char*)d_ws;
    size_t o = 0;
    auto alloc = [&](size_t bytes) -> void* {
        void* p = ws + o;
        o = (o + bytes + 255) & ~(size_t)255;
        return p;
    };
    unsigned short* hb  = (unsigned short*)alloc((size_t)N_NODES * D_HID * 2);
    float* s1       = (float*)alloc((size_t)N_NODES * 4);
    float* s2       = (float*)alloc((size_t)N_NODES * 4);
    int*   bcnt     = (int*)alloc((size_t)NB * BCNT_STRIDE * 4);
    int2*  binned   = (int2*)alloc((size_t)NB * CAP * 8);

    hipMemsetAsync(bcnt, 0, (size_t)NB * BCNT_STRIDE * 4, stream);

    node_kernel<<<1250, 256, 0, stream>>>(nf, w_w, w_b, a_w, hb, s1, s2);
    edge_bin_kernel<<<EB_NCHUNK, EB_BLK, 0, stream>>>(ef, eidx, ew_w, ew_b, a_w, a_b, bcnt, binned);
    bucket_accum_kernel<<<NB, 1024, 0, stream>>>(bcnt, binned, s1, s2, hb, out);
}

// Round 19
// 142.278 us; speedup vs baseline: 1.0593x; 1.0593x over previous
//
#include <hip/hip_runtime.h>
#include <math.h>

#define N_NODES 80000
#define N_EDGES 1280000
#define D_NODE  128
#define D_EDGE  32
#define D_HID   64
#define NEG_SLOPE 0.2f
#define NB 313              // buckets of 256 target nodes
#define CAP 4608            // slab capacity per bucket (mean 4096 + 8 sigma)
#define BCNT_STRIDE 16      // one counter per 64B line
#define EB_BLK 512
#define EB_CHUNK 2048
#define EB_NCHUNK (N_EDGES / EB_CHUNK)   // 625, exact

__device__ inline float waveReduceSum(float v) {
    #pragma unroll
    for (int o = 32; o > 0; o >>= 1) v += __shfl_xor(v, o);
    return v;
}
__device__ inline unsigned short f2bf(float f) {   // round-to-nearest-even bf16
    unsigned u = __float_as_uint(f);
    return (unsigned short)((u + 0x7FFF + ((u >> 16) & 1)) >> 16);
}
__device__ inline float bf2f(unsigned short v) {
    return __uint_as_float(((unsigned)v) << 16);
}

// h(bf16) = nf @ W + b; s1 = h . a1; s2 = h . a2 (f32, pre-rounding).
// Block 0 additionally zeros bcnt (replaces the standalone memset dispatch;
// stream ordering makes it visible to edge_bin).
__global__ __launch_bounds__(256) void node_kernel(
        const float* __restrict__ nf, const float* __restrict__ w_w,
        const float* __restrict__ w_b, const float* __restrict__ a_w,
        unsigned short* __restrict__ hb, float* __restrict__ s1, float* __restrict__ s2,
        int* __restrict__ bcnt) {
    __shared__ float Ws[D_HID * D_NODE];   // 32 KB, XOR-swizzled W^T
    __shared__ float Xs[32][D_NODE];       // 16 KB
    if (blockIdx.x == 0) {
        for (int i = threadIdx.x; i < NB * BCNT_STRIDE; i += 256) bcnt[i] = 0;
    }
    for (int i = threadIdx.x; i < D_NODE * D_HID; i += 256) {
        int k = i >> 6, d = i & 63;        // w_w[k][d], row-major [128][64]
        Ws[d * D_NODE + (((k >> 2) ^ (d & 7)) << 2) + (k & 3)] = w_w[i];
    }
    int lane = threadIdx.x & 63;
    int wv   = threadIdx.x >> 6;
    float wb = w_b[lane];
    float a1 = a_w[lane];
    float a2 = a_w[D_HID + lane];
    const float* wrow = &Ws[lane * D_NODE];
    const int nTiles = N_NODES / 32;       // 2500, exact
    for (int tile = blockIdx.x; tile < nTiles; tile += gridDim.x) {
        int n0 = tile * 32;
        __syncthreads();
        {
            const float4* src = (const float4*)(nf + (size_t)n0 * D_NODE);
            float4* dst = (float4*)&Xs[0][0];
            #pragma unroll
            for (int j = 0; j < 4; ++j)
                dst[threadIdx.x + 256 * j] = src[threadIdx.x + 256 * j];
        }
        __syncthreads();
        float acc[8] = {0.f, 0.f, 0.f, 0.f, 0.f, 0.f, 0.f, 0.f};
        const float* xs = &Xs[wv * 8][0];
        #pragma unroll 4
        for (int k4 = 0; k4 < 32; ++k4) {
            float4 w = *(const float4*)&wrow[(k4 ^ (lane & 7)) << 2];
            #pragma unroll
            for (int n = 0; n < 8; ++n) {
                float4 x = *(const float4*)&xs[n * D_NODE + (k4 << 2)];
                acc[n] += w.x * x.x + w.y * x.y + w.z * x.z + w.w * x.w;
            }
        }
        #pragma unroll
        for (int n = 0; n < 8; ++n) {
            int node = n0 + wv * 8 + n;
            float hv = acc[n] + wb;
            hb[(size_t)node * D_HID + lane] = f2bf(hv);
            float r1 = waveReduceSum(hv * a1);
            float r2 = waveReduceSum(hv * a2);
            if (lane == 0) { s1[node] = r1; s2[node] = r2; }
        }
    }
}

// Fused edge partial-score + bucket binning (R16, best measured):
// Phase A: coalesced eidx loads (tg/nb in registers), full-lane s2[nbr] gather, hist.
// Phase B: ef stream dot via 4-lane quads. Phase C: reserve + local scan.
// Phase D: LDS-permute into slab order, then linear ascending-address stores.
__global__ __launch_bounds__(EB_BLK) void edge_bin_kernel(
        const float* __restrict__ ef, const int* __restrict__ eidx,
        const float* __restrict__ s2v,
        const float* __restrict__ ew_w, const float* __restrict__ ew_b,
        const float* __restrict__ a_w, const float* __restrict__ a_b,
        int* __restrict__ bcnt, int2* __restrict__ binned) {
    __shared__ float cs[D_EDGE];
    __shared__ float besp;
    __shared__ int hist[NB], gbase[NB], rank[NB];
    __shared__ int scanbuf[512];
    __shared__ float sq [EB_CHUNK];   // 8 KB: q = bes + s2[nbr] + ef.c
    __shared__ int2  sval[EB_CHUNK];  // 16 KB: {meta, q bits} in slab order
    __shared__ int   sdst[EB_CHUNK];  // 8 KB: global dest index in slab order
    int tid = threadIdx.x;
    if (tid < D_EDGE) {
        float s = 0.f;
        #pragma unroll
        for (int d = 0; d < D_HID; ++d) s += ew_w[tid * D_HID + d] * a_w[2 * D_HID + d];
        cs[tid] = s;
    } else if (tid == D_EDGE) {
        float s = 0.f;
        #pragma unroll
        for (int d = 0; d < D_HID; ++d) s += ew_b[d] * a_w[2 * D_HID + d];
        besp = s + a_b[0];
    }
    for (int i = tid; i < NB; i += EB_BLK) { hist[i] = 0; rank[i] = 0; }
    __syncthreads();
    float bes = besp;
    int e0 = blockIdx.x * EB_CHUNK;        // one chunk per block, grid = 625
    // ---- Phase A: index loads (tg/nb -> registers) + s2 gather + hist ----
    int RT[4], RN[4];
    #pragma unroll
    for (int k = 0; k < 4; ++k) {
        int idx = k * EB_BLK + tid;
        int e = e0 + idx;                  // coalesced
        RT[k] = eidx[e];
        RN[k] = eidx[N_EDGES + e];
        sq[idx] = bes + s2v[RN[k]];        // gather issued by all 64 lanes
        atomicAdd(&hist[RT[k] >> 8], 1);
    }
    __syncthreads();
    // ---- Phase B: ef stream dot, 128 edges per round ----
    {
        int qd = tid >> 2, j = tid & 3;
        const float4 c1 = *(const float4*)&cs[j * 4];
        const float4 c2 = *(const float4*)&cs[16 + j * 4];
        const float4* f4 = (const float4*)ef;
        #pragma unroll 2
        for (int rr = 0; rr < EB_CHUNK / 128; ++rr) {
            int idx = rr * 128 + qd;
            int e = e0 + idx;
            float4 fa = f4[(size_t)e * 8 + j];
            float4 fb = f4[(size_t)e * 8 + 4 + j];
            float p = fa.x * c1.x + fa.y * c1.y + fa.z * c1.z + fa.w * c1.w
                    + fb.x * c2.x + fb.y * c2.y + fb.z * c2.z + fb.w * c2.w;
            p += __shfl_xor(p, 1);
            p += __shfl_xor(p, 2);                    // all 4 lanes: full dot
            if (j == 0) sq[idx] += p;                 // one writer per idx
        }
    }
    __syncthreads();
    // ---- Phase C: reserve global ranges + local exclusive scan of hist ----
    for (int i = tid; i < NB; i += EB_BLK) {
        int cc = hist[i];
        if (cc) gbase[i] = i * CAP + atomicAdd(&bcnt[i * BCNT_STRIDE], cc);
    }
    scanbuf[tid] = (tid < NB) ? hist[tid] : 0;
    __syncthreads();
    for (int ofs = 1; ofs < 512; ofs <<= 1) {
        int t = (tid >= (unsigned)ofs) ? scanbuf[tid - ofs] : 0;
        __syncthreads();
        scanbuf[tid] += t;
        __syncthreads();
    }
    // ---- Phase D1: scatter {meta,q}+dest into LDS slab (slab order) ----
    #pragma unroll
    for (int k = 0; k < 4; ++k) {
        int idx = k * EB_BLK + tid;
        int tg = RT[k];
        int b  = tg >> 8;
        int r  = atomicAdd(&rank[b], 1);
        int slot = scanbuf[b] - hist[b] + r;
        sval[slot] = make_int2(((tg & 255) << 17) | RN[k],
                               __float_as_int(sq[idx]));
        sdst[slot] = gbase[b] + r;
    }
    __syncthreads();
    // ---- Phase D2: linear sweep -> ascending-address coalesced stores ----
    #pragma unroll
    for (int k = 0; k < 4; ++k) {
        int i = k * EB_BLK + tid;
        binned[sdst[i]] = sval[i];
    }
}

// Merged CSR + accum (R15/R16): one block per bucket; hist + scan + permute
// into 36 KB LDS slab; 64 x 16-lane groups, degree-matched gather.
// q already contains ef.c + bes + s2[nbr]; s = s1[node] + q.
__global__ __launch_bounds__(1024) void bucket_accum_kernel(
        const int* __restrict__ bcnt, const int2* __restrict__ binned,
        const float* __restrict__ s1, const unsigned short* __restrict__ hb,
        float* __restrict__ out) {
    __shared__ int nhist[256], buf[256], sbase[256], ncur[256];
    __shared__ int2 slab[CAP];        // 36 KB
    int tid = threadIdx.x;
    int b = blockIdx.x;
    int in0 = b * CAP;
    int cnt = bcnt[b * BCNT_STRIDE];
    if (tid < 256) nhist[tid] = 0;
    __syncthreads();
    for (int i = tid; i < cnt; i += 1024)
        atomicAdd(&nhist[binned[in0 + i].x >> 17], 1);
    __syncthreads();
    if (tid < 256) buf[tid] = nhist[tid];
    __syncthreads();
    for (int ofs = 1; ofs < 256; ofs <<= 1) {
        int t = 0;
        if (tid < 256 && tid >= ofs) t = buf[tid - ofs];
        __syncthreads();
        if (tid < 256) buf[tid] += t;
        __syncthreads();
    }
    if (tid < 256) {
        int excl = buf[tid] - nhist[tid];
        sbase[tid] = excl;
        ncur[tid]  = excl;
    }
    __syncthreads();
    for (int i = tid; i < cnt; i += 1024) {
        int2 p = binned[in0 + i];
        int r = atomicAdd(&ncur[p.x >> 17], 1);
        slab[r] = make_int2(p.x & 0x1FFFF, p.y);   // {nbr, q bits}
    }
    __syncthreads();
    int grp = tid >> 4;               // 0..63
    int li  = tid & 15;
    int wl  = ((tid & 63) >> 4) << 4; // group base lane within wave
    for (int nl = grp; nl < 256; nl += 64) {
        int node = b * 256 + nl;
        if (node >= N_NODES) break;
        int base = sbase[nl];
        int cn   = nhist[nl];
        float s1i = s1[node];
        float ax = 0.f, ay = 0.f, az = 0.f, aw = 0.f, sumex = 0.f;
        for (int c0 = 0; c0 < cn; c0 += 16) {
            int i = c0 + li;
            int nc = min(16, cn - c0);
            float exv = 0.f; int nbv = 0;
            if (i < cn) {
                int2 p = slab[base + i];
                nbv = p.x;
                float s = s1i + __int_as_float(p.y);
                s = (s > 0.f) ? s : NEG_SLOPE * s;
                exv = __expf(s);      // un-normalized (exp safe in f32)
            }
            sumex += exv;
            for (int jj = 0; jj < nc; ++jj) {
                float w  = __shfl(exv, wl + jj);
                int   nb = __shfl(nbv, wl + jj);
                uint2 v = *(const uint2*)&hb[(size_t)nb * D_HID + li * 4];
                ax += w * bf2f((unsigned short)(v.x & 0xFFFF));
                ay += w * bf2f((unsigned short)(v.x >> 16));
                az += w * bf2f((unsigned short)(v.y & 0xFFFF));
                aw += w * bf2f((unsigned short)(v.y >> 16));
            }
        }
        #pragma unroll
        for (int o = 8; o > 0; o >>= 1) sumex += __shfl_xor(sumex, o);
        float4 o4;
        if (cn == 0) {
            o4 = make_float4(0.f, 0.f, 0.f, 0.f);
        } else {
            o4.x = ax / sumex; o4.y = ay / sumex; o4.z = az / sumex; o4.w = aw / sumex;
            o4.x = (o4.x > 0.f) ? o4.x : (__expf(o4.x) - 1.f);
            o4.y = (o4.y > 0.f) ? o4.y : (__expf(o4.y) - 1.f);
            o4.z = (o4.z > 0.f) ? o4.z : (__expf(o4.z) - 1.f);
            o4.w = (o4.w > 0.f) ? o4.w : (__expf(o4.w) - 1.f);
        }
        ((float4*)out)[(size_t)node * 16 + li] = o4;
    }
}

extern "C" void kernel_launch(void* const* d_in, const int* in_sizes, int n_in,
                              void* d_out, int out_size, void* d_ws, size_t ws_size,
                              hipStream_t stream) {
    const float* nf   = (const float*)d_in[0];
    const float* ef   = (const float*)d_in[1];
    const int*   eidx = (const int*)d_in[2];
    const float* w_w  = (const float*)d_in[3];
    const float* w_b  = (const float*)d_in[4];
    const float* ew_w = (const float*)d_in[5];
    const float* ew_b = (const float*)d_in[6];
    const float* a_w  = (const float*)d_in[7];
    const float* a_b  = (const float*)d_in[8];
    float* out = (float*)d_out;

    char* ws = (char*)d_ws;
    size_t o = 0;
    auto alloc = [&](size_t bytes) -> void* {
        void* p = ws + o;
        o = (o + bytes + 255) & ~(size_t)255;
        return p;
    };
    unsigned short* hb  = (unsigned short*)alloc((size_t)N_NODES * D_HID * 2);
    float* s1       = (float*)alloc((size_t)N_NODES * 4);
    float* s2       = (float*)alloc((size_t)N_NODES * 4);
    int*   bcnt     = (int*)alloc((size_t)NB * BCNT_STRIDE * 4);
    int2*  binned   = (int2*)alloc((size_t)NB * CAP * 8);

    node_kernel<<<1250, 256, 0, stream>>>(nf, w_w, w_b, a_w, hb, s1, s2, bcnt);
    edge_bin_kernel<<<EB_NCHUNK, EB_BLK, 0, stream>>>(ef, eidx, s2, ew_w, ew_b, a_w, a_b, bcnt, binned);
    bucket_accum_kernel<<<NB, 1024, 0, stream>>>(bcnt, binned, s1, hb, out);
}